// Round 5
// baseline (309.008 us; speedup 1.0000x reference)
//
#include <hip/hip_runtime.h>
#include <stdint.h>

typedef __bf16 bf16x8 __attribute__((ext_vector_type(8)));
typedef float f32x4 __attribute__((ext_vector_type(4)));
typedef unsigned short ushort_t;

#define MFMA16(a,b,c) __builtin_amdgcn_mfma_f32_16x16x32_bf16((a),(b),(c),0,0,0)

__device__ __forceinline__ unsigned short f2bf(float f){
    unsigned u = __builtin_bit_cast(unsigned, f);
    u += 0x7fffu + ((u>>16)&1u);            // RNE
    return (unsigned short)(u>>16);
}
// pack two fp32 -> bf16 pair in one uint (round-half-up)
__device__ __forceinline__ unsigned pack2bf(float lo, float hi){
    unsigned a = __builtin_bit_cast(unsigned, lo) + 0x8000u;
    unsigned b = __builtin_bit_cast(unsigned, hi) + 0x8000u;
    return __builtin_amdgcn_perm(b, a, 0x07060302u);
}
__device__ __forceinline__ float fexp2(float x){
#if __has_builtin(__builtin_amdgcn_exp2f)
    return __builtin_amdgcn_exp2f(x);       // raw v_exp_f32
#else
    return exp2f(x);
#endif
}

// async global->LDS, 16B per lane; lds = wave-uniform chunk base
__device__ __forceinline__ void async16(ushort_t* lds, const ushort_t* g){
#if __has_builtin(__builtin_amdgcn_global_load_lds)
    __builtin_amdgcn_global_load_lds(
        (const __attribute__((address_space(1))) void*)g,
        (__attribute__((address_space(3))) void*)lds, 16, 0, 0);
#else
    const int l = (int)(threadIdx.x & 63u);
    *(uint4*)(lds + (size_t)l*8) = *(const uint4*)g;
#endif
}

// ---------------------------------------------------------------------------
// fp32 -> bf16 bulk convert (8 elements/thread)
// ---------------------------------------------------------------------------
__global__ __launch_bounds__(256) void convert_x(const float* __restrict__ src,
                                                 ushort_t* __restrict__ dst){
    size_t i = ((size_t)blockIdx.x*256 + threadIdx.x)*8;
    float4 a = *(const float4*)(src + i);
    float4 b = *(const float4*)(src + i + 4);
    uint4 o;
    o.x = pack2bf(a.x, a.y); o.y = pack2bf(a.z, a.w);
    o.z = pack2bf(b.x, b.y); o.w = pack2bf(b.z, b.w);
    *(uint4*)(dst + i) = o;
}

// ---------------------------------------------------------------------------
// W transposes (z = 0..4): fp32 [1024][512] -> bf16 [512][1024]
// ---------------------------------------------------------------------------
__global__ __launch_bounds__(256) void transpose_w(
    const float* __restrict__ w0, const float* __restrict__ w1,
    const float* __restrict__ w2, const float* __restrict__ w3,
    const float* __restrict__ w4,
    ushort_t* __restrict__ Wt1, ushort_t* __restrict__ Wt2)
{
    int z = blockIdx.z;
    const float* src; ushort_t* dst;
    if (z < 3)  { src = (z==0)?w0:((z==1)?w1:w2); dst = Wt1 + (size_t)z*512*1024; }
    else        { src = (z==3)?w3:w4;             dst = Wt2 + (size_t)(z-3)*512*1024; }
    const int N = 512;
    int k0 = blockIdx.x*32, n0 = blockIdx.y*32;
    __shared__ float T[32][33];
    int t = threadIdx.x;
    int kr = t>>3, nc = (t&7)*4;
    float4 v = *(const float4*)(src + (size_t)(k0+kr)*N + n0 + nc);
    T[kr][nc] = v.x; T[kr][nc+1] = v.y; T[kr][nc+2] = v.z; T[kr][nc+3] = v.w;
    __syncthreads();
    int nr = t>>3, kc = (t&7)*4;
    uint2 o;
    o.x = pack2bf(T[kc][nr],   T[kc+1][nr]);
    o.y = pack2bf(T[kc+2][nr], T[kc+3][nr]);
    *(uint2*)(dst + (size_t)(n0+nr)*1024 + k0 + kc) = o;
}

// ---------------------------------------------------------------------------
// Wo transpose with k-dim un-permutation: dst[n][64h + d'] = src[64h + invpi(d')][n]
// invpi(d') = ((d'&3)<<4) | (d'>>2)
// ---------------------------------------------------------------------------
__global__ __launch_bounds__(256) void transpose_wo(
    const float* __restrict__ src, ushort_t* __restrict__ dst)
{
    __shared__ float T[64][33];
    const int k0 = blockIdx.x*64;   // one head block
    const int n0 = blockIdx.y*32;
    const int t = threadIdx.x;
    const int kr = t>>3, nc = (t&7)*4;
#pragma unroll
    for (int hf = 0; hf < 2; ++hf){
        float4 v = *(const float4*)(src + (size_t)(k0 + hf*32 + kr)*1024 + n0 + nc);
        T[hf*32+kr][nc]   = v.x; T[hf*32+kr][nc+1] = v.y;
        T[hf*32+kr][nc+2] = v.z; T[hf*32+kr][nc+3] = v.w;
    }
    __syncthreads();
    const int nr = t>>3, kc = (t&7)*8;
    ushort_t tmp[8];
#pragma unroll
    for (int e = 0; e < 8; ++e){
        int dp = kc + e;
        int d  = ((dp&3)<<4) | (dp>>2);
        tmp[e] = f2bf(T[d][nr]);
    }
    *(uint4*)(dst + (size_t)(n0+nr)*512 + k0 + kc) = *(uint4*)tmp;
}

// ---------------------------------------------------------------------------
// bf16 GEMM: 128x128 tile, BK=32, single-barrier LDS double-buffer.
// A[M][KD] @ Bt[N][KD]^T.
// MODE 0: N=1536 -> Q(scaled)|K|Vtile scatter (pi-permuted d).
// MODE 1: N=1024 -> K|Vtile at key offset koff.  MODE 2: fp32 out + bias.
// V layout: [bh][keytile][d'][64 slots], slot = 32(mt>>1)+4(mt&1)+8quad+r
// (the PV B-operand key permutation, baked in at produce time).
// ---------------------------------------------------------------------------
template<int KD, int MODE>
__global__ __launch_bounds__(256) void gemm_bt(
    const ushort_t* __restrict__ A, const ushort_t* __restrict__ Bt,
    ushort_t* __restrict__ Qp, ushort_t* __restrict__ Kp, ushort_t* __restrict__ Vtp,
    float* __restrict__ outF, const float* __restrict__ bias, int koff)
{
    __shared__ ushort_t As[2][128][32];
    __shared__ ushort_t Bs[2][128][32];
    const int t = threadIdx.x;
    const int m0 = blockIdx.x*128, n0 = blockIdx.y*128;
    const int w = t>>6, l = t&63;
    const int quad = l>>4, lc = l&15;
    const int wr = (w>>1)*64, wc = (w&1)*64;

    f32x4 acc[4][4] = {};

    const int crow = l>>2;
    const int kseg = (l&3)*8;
    const ushort_t* gA0 = A  + (size_t)(m0 + w*32      + crow)*KD + kseg;
    const ushort_t* gA1 = A  + (size_t)(m0 + w*32 + 16 + crow)*KD + kseg;
    const ushort_t* gB0 = Bt + (size_t)(n0 + w*32      + crow)*KD + kseg;
    const ushort_t* gB1 = Bt + (size_t)(n0 + w*32 + 16 + crow)*KD + kseg;

    const int NK = KD/32;

    async16(&As[0][w*32][0],    gA0);
    async16(&As[0][w*32+16][0], gA1);
    async16(&Bs[0][w*32][0],    gB0);
    async16(&Bs[0][w*32+16][0], gB1);
    __syncthreads();

    for (int kk = 0; kk < NK; ++kk) {
        const int cur = kk & 1;
        if (kk + 1 < NK) {
            const int k0 = (kk+1)*32;
            const int nx = cur ^ 1;
            async16(&As[nx][w*32][0],    gA0 + k0);
            async16(&As[nx][w*32+16][0], gA1 + k0);
            async16(&Bs[nx][w*32][0],    gB0 + k0);
            async16(&Bs[nx][w*32+16][0], gB1 + k0);
        }
        bf16x8 af[4], bfv[4];
#pragma unroll
        for (int i = 0; i < 4; ++i) {
            af[i]  = *(const bf16x8*)&As[cur][wr + i*16 + lc][quad*8];
            bfv[i] = *(const bf16x8*)&Bs[cur][wc + i*16 + lc][quad*8];
        }
#pragma unroll
        for (int mt = 0; mt < 4; ++mt)
#pragma unroll
            for (int nt = 0; nt < 4; ++nt)
                acc[mt][nt] = MFMA16(af[mt], bfv[nt], acc[mt][nt]);
        __syncthreads();
    }

    if (MODE == 2) {
        float bv[4];
#pragma unroll
        for (int nt = 0; nt < 4; ++nt) bv[nt] = bias[n0 + wc + nt*16 + lc];
#pragma unroll
        for (int mt = 0; mt < 4; ++mt) {
            const int row = m0 + wr + mt*16 + quad*4;
#pragma unroll
            for (int nt = 0; nt < 4; ++nt) {
                const int col = n0 + wc + nt*16 + lc;
#pragma unroll
                for (int r = 0; r < 4; ++r)
                    outF[(size_t)(row+r)*1024 + col] = acc[mt][nt][r] + bv[nt];
            }
        }
    } else {
        const int sub = (MODE == 0) ? (n0>>9) : (1 + (n0>>9)); // 0=Q,1=K,2=V
        const int hh  = ((n0 + wc)>>6) & 7;
        const int dp  = 4*lc;
        const float QSC = 0.18033688011112042f;                // 0.125*log2(e)
        if (sub == 0) {
#pragma unroll
            for (int mt = 0; mt < 4; ++mt) {
                const int row = m0 + wr + mt*16 + quad*4;
                const int b = row>>11, i = row & 2047;
#pragma unroll
                for (int r = 0; r < 4; ++r) {
                    uint2 o;
                    o.x = pack2bf(acc[mt][0][r]*QSC, acc[mt][1][r]*QSC);
                    o.y = pack2bf(acc[mt][2][r]*QSC, acc[mt][3][r]*QSC);
                    *(uint2*)(Qp + ((size_t)(b*8+hh)*2048 + i + r)*64 + dp) = o;
                }
            }
        } else if (sub == 1) {
#pragma unroll
            for (int mt = 0; mt < 4; ++mt) {
                const int row = m0 + wr + mt*16 + quad*4;
                const int b = row>>11, i = row & 2047;
#pragma unroll
                for (int r = 0; r < 4; ++r) {
                    uint2 o;
                    o.x = pack2bf(acc[mt][0][r], acc[mt][1][r]);
                    o.y = pack2bf(acc[mt][2][r], acc[mt][3][r]);
                    *(uint2*)(Kp + ((size_t)(b*8+hh)*4096 + koff + i + r)*64 + dp) = o;
                }
            }
        } else {
#pragma unroll
            for (int mt = 0; mt < 4; ++mt) {
                const int row = m0 + wr + mt*16 + quad*4;
                const int b = row>>11, i = row & 2047;
                const int tile = (koff + i) >> 6;
                const int slot = 32*(mt>>1) + 4*(mt&1) + 8*quad;
#pragma unroll
                for (int nt = 0; nt < 4; ++nt) {
                    uint2 o;
                    o.x = pack2bf(acc[mt][nt][0], acc[mt][nt][1]);
                    o.y = pack2bf(acc[mt][nt][2], acc[mt][nt][3]);
                    *(uint2*)(Vtp + (((size_t)(b*8+hh)*64 + tile)*64 + dp + nt)*64 + slot) = o;
                }
            }
        }
    }
}

// ---------------------------------------------------------------------------
// Flash attention, S^T formulation, no-max softmax, 64 q/block,
// grid (32,32)=1024 blocks -> 4 blocks/CU. Single-barrier LDS double-buffer
// with register prefetch; K and V tiles are contiguous 8 KB in global.
// ---------------------------------------------------------------------------
__global__ __launch_bounds__(256) void flash_attn(
    const ushort_t* __restrict__ Q, const ushort_t* __restrict__ Kg,
    const ushort_t* __restrict__ Vt, ushort_t* __restrict__ AO)
{
    __shared__ ushort_t Ks[2][64][72];
    __shared__ ushort_t Vs[2][64][72];
    const int bh = blockIdx.x, qt = blockIdx.y;
    const int b = bh>>3, h = bh&7;
    const int t = threadIdx.x, wv = t>>6, l = t&63;
    const int quad = l>>4, lc = l&15;

    // Q fragments (B-operand); Q pre-scaled by 0.125*log2e
    const ushort_t* qbase = Q + ((size_t)bh*2048 + qt*64 + wv*16 + lc)*64;
    bf16x8 qf0 = *(const bf16x8*)(qbase + quad*8);
    bf16x8 qf1 = *(const bf16x8*)(qbase + 32 + quad*8);

    const ushort_t* Kb = Kg + (size_t)bh*4096*64;
    const ushort_t* Vb = Vt + (size_t)bh*64*4096;

    // staging: thread copies 32 B of K tile + 32 B of V tile (contiguous)
    const int srow = t>>2, sseg = (t&3)*16;
    const ushort_t* kst = Kb + (size_t)t*16;
    const ushort_t* vst = Vb + (size_t)t*16;

    float l_i = 0.0f;
    f32x4 oacc[4] = {};

    uint4 ka  = *(const uint4*)(kst);
    uint4 kb2 = *(const uint4*)(kst + 8);
    uint4 va  = *(const uint4*)(vst);
    uint4 vb2 = *(const uint4*)(vst + 8);

    for (int jt = 0; jt < 64; ++jt) {
        const int cur = jt & 1;
        ushort_t* ksd = &Ks[cur][srow][sseg];
        ushort_t* vsd = &Vs[cur][srow][sseg];
        *(uint4*)ksd     = ka;
        *(uint4*)(ksd+8) = kb2;
        *(uint4*)vsd     = va;
        *(uint4*)(vsd+8) = vb2;
        __syncthreads();
        if (jt < 63) {
            const size_t j0 = (size_t)(jt+1)*4096;
            ka  = *(const uint4*)(kst + j0);
            kb2 = *(const uint4*)(kst + j0 + 8);
            va  = *(const uint4*)(vst + j0);
            vb2 = *(const uint4*)(vst + j0 + 8);
        }

        // S^T: keys (rows) x q (cols)
        f32x4 st[4];
#pragma unroll
        for (int kt = 0; kt < 4; ++kt) {
            bf16x8 kf0 = *(const bf16x8*)&Ks[cur][kt*16 + lc][quad*8];
            bf16x8 kf1 = *(const bf16x8*)&Ks[cur][kt*16 + lc][32 + quad*8];
            f32x4 z = {};
            z = MFMA16(kf0, qf0, z);
            z = MFMA16(kf1, qf1, z);
            st[kt] = z;
        }

        // no-max softmax: p = exp2(st)
        union { unsigned u[8]; bf16x8 v[2]; } pf;
        float rs = 0.0f;
#pragma unroll
        for (int kt = 0; kt < 4; ++kt) {
            float a0 = fexp2(st[kt][0]), a1 = fexp2(st[kt][1]);
            float a2 = fexp2(st[kt][2]), a3 = fexp2(st[kt][3]);
            rs += (a0 + a1) + (a2 + a3);
            pf.u[kt*2]   = pack2bf(a0, a1);
            pf.u[kt*2+1] = pack2bf(a2, a3);
        }
        l_i += rs;

        // O^T accumulate
#pragma unroll
        for (int dt = 0; dt < 4; ++dt) {
            bf16x8 vf0 = *(const bf16x8*)&Vs[cur][dt*16 + lc][quad*8];
            bf16x8 vf1 = *(const bf16x8*)&Vs[cur][dt*16 + lc][32 + quad*8];
            oacc[dt] = MFMA16(vf0, pf.v[0], oacc[dt]);
            oacc[dt] = MFMA16(vf1, pf.v[1], oacc[dt]);
        }
    }

    l_i += __shfl_xor(l_i, 16);
    l_i += __shfl_xor(l_i, 32);
    float linv = 1.0f / l_i;

    const int qg = qt*64 + wv*16 + lc;
    ushort_t* aod = AO + ((size_t)b*2048 + qg)*512 + h*64 + quad*4;
#pragma unroll
    for (int dt = 0; dt < 4; ++dt) {
        uint2 o;
        o.x = pack2bf(oacc[dt][0]*linv, oacc[dt][1]*linv);
        o.y = pack2bf(oacc[dt][2]*linv, oacc[dt][3]*linv);
        *(uint2*)(aod + dt*16) = o;
    }
}

// ---------------------------------------------------------------------------
extern "C" void kernel_launch(void* const* d_in, const int* in_sizes, int n_in,
                              void* d_out, int out_size, void* d_ws, size_t ws_size,
                              hipStream_t stream)
{
    const float* x1  = (const float*)d_in[0];
    const float* x2  = (const float*)d_in[1];
    const float* Wq1 = (const float*)d_in[2];
    const float* Wk1 = (const float*)d_in[3];
    const float* Wv1 = (const float*)d_in[4];
    const float* Wk2 = (const float*)d_in[5];
    const float* Wv2 = (const float*)d_in[6];
    const float* Wo  = (const float*)d_in[7];
    const float* bo  = (const float*)d_in[8];
    float* out = (float*)d_out;

    ushort_t* ws  = (ushort_t*)d_ws;
    ushort_t* Xc1 = ws;                 // 8,388,608
    ushort_t* Xc2 = Xc1 + 8388608;      // 8,388,608 (reused as AO after attn)
    ushort_t* Wt1 = Xc2 + 8388608;      // 1,572,864
    ushort_t* Wt2 = Wt1 + 1572864;      // 1,048,576
    ushort_t* Wot = Wt2 + 1048576;      //   524,288
    ushort_t* Qp  = Wot + 524288;       // 4,194,304
    ushort_t* Kp  = Qp  + 4194304;      // 8,388,608
    ushort_t* Vtp = Kp  + 8388608;      // 8,388,608
    ushort_t* AOp = Xc2;

    convert_x<<<4096, 256, 0, stream>>>(x1, Xc1);
    convert_x<<<4096, 256, 0, stream>>>(x2, Xc2);
    transpose_w<<<dim3(32,16,5), 256, 0, stream>>>(Wq1,Wk1,Wv1,Wk2,Wv2, Wt1,Wt2);
    transpose_wo<<<dim3(8,32), 256, 0, stream>>>(Wo, Wot);

    gemm_bt<1024,0><<<dim3(64,12), 256, 0, stream>>>(Xc1, Wt1, Qp, Kp, Vtp, nullptr, nullptr, 0);
    gemm_bt<1024,1><<<dim3(64,8),  256, 0, stream>>>(Xc2, Wt2, Qp, Kp, Vtp, nullptr, nullptr, 2048);

    flash_attn<<<dim3(32,32), 256, 0, stream>>>(Qp, Kp, Vtp, AOp);

    gemm_bt<512,2><<<dim3(64,8), 256, 0, stream>>>(AOp, Wot, nullptr, nullptr, nullptr, out, bo, 0);
}

// Round 6
// 297.837 us; speedup vs baseline: 1.0375x; 1.0375x over previous
//
#include <hip/hip_runtime.h>
#include <stdint.h>

typedef __bf16 bf16x8 __attribute__((ext_vector_type(8)));
typedef float f32x4 __attribute__((ext_vector_type(4)));
typedef unsigned short ushort_t;

#define MFMA16(a,b,c) __builtin_amdgcn_mfma_f32_16x16x32_bf16((a),(b),(c),0,0,0)

__device__ __forceinline__ unsigned short f2bf(float f){
    unsigned u = __builtin_bit_cast(unsigned, f);
    u += 0x7fffu + ((u>>16)&1u);            // RNE
    return (unsigned short)(u>>16);
}
__device__ __forceinline__ unsigned pack2bf(float lo, float hi){
    unsigned a = __builtin_bit_cast(unsigned, lo) + 0x8000u;
    unsigned b = __builtin_bit_cast(unsigned, hi) + 0x8000u;
    return __builtin_amdgcn_perm(b, a, 0x07060302u);
}
__device__ __forceinline__ float fexp2(float x){
#if __has_builtin(__builtin_amdgcn_exp2f)
    return __builtin_amdgcn_exp2f(x);
#else
    return exp2f(x);
#endif
}

__device__ __forceinline__ void async16(ushort_t* lds, const ushort_t* g){
#if __has_builtin(__builtin_amdgcn_global_load_lds)
    __builtin_amdgcn_global_load_lds(
        (const __attribute__((address_space(1))) void*)g,
        (__attribute__((address_space(3))) void*)lds, 16, 0, 0);
#else
    const int l = (int)(threadIdx.x & 63u);
    *(uint4*)(lds + (size_t)l*8) = *(const uint4*)g;
#endif
}

// ---------------------------------------------------------------------------
__global__ __launch_bounds__(256) void convert_x(const float* __restrict__ src,
                                                 ushort_t* __restrict__ dst){
    size_t i = ((size_t)blockIdx.x*256 + threadIdx.x)*8;
    float4 a = *(const float4*)(src + i);
    float4 b = *(const float4*)(src + i + 4);
    uint4 o;
    o.x = pack2bf(a.x, a.y); o.y = pack2bf(a.z, a.w);
    o.z = pack2bf(b.x, b.y); o.w = pack2bf(b.z, b.w);
    *(uint4*)(dst + i) = o;
}

// ---------------------------------------------------------------------------
__global__ __launch_bounds__(256) void transpose_w(
    const float* __restrict__ w0, const float* __restrict__ w1,
    const float* __restrict__ w2, const float* __restrict__ w3,
    const float* __restrict__ w4,
    ushort_t* __restrict__ Wt1, ushort_t* __restrict__ Wt2)
{
    int z = blockIdx.z;
    const float* src; ushort_t* dst;
    if (z < 3)  { src = (z==0)?w0:((z==1)?w1:w2); dst = Wt1 + (size_t)z*512*1024; }
    else        { src = (z==3)?w3:w4;             dst = Wt2 + (size_t)(z-3)*512*1024; }
    const int N = 512;
    int k0 = blockIdx.x*32, n0 = blockIdx.y*32;
    __shared__ float T[32][33];
    int t = threadIdx.x;
    int kr = t>>3, nc = (t&7)*4;
    float4 v = *(const float4*)(src + (size_t)(k0+kr)*N + n0 + nc);
    T[kr][nc] = v.x; T[kr][nc+1] = v.y; T[kr][nc+2] = v.z; T[kr][nc+3] = v.w;
    __syncthreads();
    int nr = t>>3, kc = (t&7)*4;
    uint2 o;
    o.x = pack2bf(T[kc][nr],   T[kc+1][nr]);
    o.y = pack2bf(T[kc+2][nr], T[kc+3][nr]);
    *(uint2*)(dst + (size_t)(n0+nr)*1024 + k0 + kc) = o;
}

// ---------------------------------------------------------------------------
// Wo transpose with k-dim un-permutation: dst[n][64h+d'] = src[64h+invpi(d')][n]
// invpi(d') = ((d'&3)<<4) | (d'>>2)
// ---------------------------------------------------------------------------
__global__ __launch_bounds__(256) void transpose_wo(
    const float* __restrict__ src, ushort_t* __restrict__ dst)
{
    __shared__ float T[64][33];
    const int k0 = blockIdx.x*64;
    const int n0 = blockIdx.y*32;
    const int t = threadIdx.x;
    const int kr = t>>3, nc = (t&7)*4;
#pragma unroll
    for (int hf = 0; hf < 2; ++hf){
        float4 v = *(const float4*)(src + (size_t)(k0 + hf*32 + kr)*1024 + n0 + nc);
        T[hf*32+kr][nc]   = v.x; T[hf*32+kr][nc+1] = v.y;
        T[hf*32+kr][nc+2] = v.z; T[hf*32+kr][nc+3] = v.w;
    }
    __syncthreads();
    const int nr = t>>3, kc = (t&7)*8;
    ushort_t tmp[8];
#pragma unroll
    for (int e = 0; e < 8; ++e){
        int dp = kc + e;
        int d  = ((dp&3)<<4) | (dp>>2);
        tmp[e] = f2bf(T[d][nr]);
    }
    *(uint4*)(dst + (size_t)(n0+nr)*512 + k0 + kc) = *(uint4*)tmp;
}

// ---------------------------------------------------------------------------
// Fused projection GEMM: grid y in [0,20). y<12: X1@Wt1 -> Q|K|V (keys 0..2047)
// y>=12: X2@Wt2 -> K|V (keys 2048..4095). 128x128 tile, BK=32, dbuf.
// V layout: [bh][keytile][d'][slot64], slot = 32(mt>>1)+4(mt&1)+8quad+r.
// ---------------------------------------------------------------------------
__global__ __launch_bounds__(256) void proj_fused(
    const ushort_t* __restrict__ X1, const ushort_t* __restrict__ X2,
    const ushort_t* __restrict__ W1, const ushort_t* __restrict__ W2,
    ushort_t* __restrict__ Qp, ushort_t* __restrict__ Kp, ushort_t* __restrict__ Vtp)
{
    __shared__ ushort_t As[2][128][32];
    __shared__ ushort_t Bs[2][128][32];
    const int t = threadIdx.x;
    const int m0 = blockIdx.x*128;
    const int y  = blockIdx.y;
    const ushort_t* A; const ushort_t* Bt; int n0, koff, sub;
    if (y < 12) { A = X1; Bt = W1; n0 = y*128;      koff = 0;    sub = n0>>9; }
    else        { A = X2; Bt = W2; n0 = (y-12)*128; koff = 2048; sub = 1 + (n0>>9); }

    const int w = t>>6, l = t&63;
    const int quad = l>>4, lc = l&15;
    const int wr = (w>>1)*64, wc = (w&1)*64;
    const int KD = 1024;

    f32x4 acc[4][4] = {};

    const int crow = l>>2;
    const int kseg = (l&3)*8;
    const ushort_t* gA0 = A  + (size_t)(m0 + w*32      + crow)*KD + kseg;
    const ushort_t* gA1 = A  + (size_t)(m0 + w*32 + 16 + crow)*KD + kseg;
    const ushort_t* gB0 = Bt + (size_t)(n0 + w*32      + crow)*KD + kseg;
    const ushort_t* gB1 = Bt + (size_t)(n0 + w*32 + 16 + crow)*KD + kseg;

    async16(&As[0][w*32][0],    gA0);
    async16(&As[0][w*32+16][0], gA1);
    async16(&Bs[0][w*32][0],    gB0);
    async16(&Bs[0][w*32+16][0], gB1);
    __syncthreads();

    for (int kk = 0; kk < 32; ++kk) {
        const int cur = kk & 1;
        if (kk + 1 < 32) {
            const int k0 = (kk+1)*32;
            const int nx = cur ^ 1;
            async16(&As[nx][w*32][0],    gA0 + k0);
            async16(&As[nx][w*32+16][0], gA1 + k0);
            async16(&Bs[nx][w*32][0],    gB0 + k0);
            async16(&Bs[nx][w*32+16][0], gB1 + k0);
        }
        bf16x8 af[4], bfv[4];
#pragma unroll
        for (int i = 0; i < 4; ++i) {
            af[i]  = *(const bf16x8*)&As[cur][wr + i*16 + lc][quad*8];
            bfv[i] = *(const bf16x8*)&Bs[cur][wc + i*16 + lc][quad*8];
        }
#pragma unroll
        for (int mt = 0; mt < 4; ++mt)
#pragma unroll
            for (int nt = 0; nt < 4; ++nt)
                acc[mt][nt] = MFMA16(af[mt], bfv[nt], acc[mt][nt]);
        __syncthreads();
    }

    const int hh = ((n0 + wc)>>6) & 7;
    const int dp = 4*lc;
    const float QSC = 0.18033688011112042f;   // 0.125*log2(e)
    if (sub == 0) {
#pragma unroll
        for (int mt = 0; mt < 4; ++mt) {
            const int row = m0 + wr + mt*16 + quad*4;
            const int b = row>>11, i = row & 2047;
#pragma unroll
            for (int r = 0; r < 4; ++r) {
                uint2 o;
                o.x = pack2bf(acc[mt][0][r]*QSC, acc[mt][1][r]*QSC);
                o.y = pack2bf(acc[mt][2][r]*QSC, acc[mt][3][r]*QSC);
                *(uint2*)(Qp + ((size_t)(b*8+hh)*2048 + i + r)*64 + dp) = o;
            }
        }
    } else if (sub == 1) {
#pragma unroll
        for (int mt = 0; mt < 4; ++mt) {
            const int row = m0 + wr + mt*16 + quad*4;
            const int b = row>>11, i = row & 2047;
#pragma unroll
            for (int r = 0; r < 4; ++r) {
                uint2 o;
                o.x = pack2bf(acc[mt][0][r], acc[mt][1][r]);
                o.y = pack2bf(acc[mt][2][r], acc[mt][3][r]);
                *(uint2*)(Kp + ((size_t)(b*8+hh)*4096 + koff + i + r)*64 + dp) = o;
            }
        }
    } else {
#pragma unroll
        for (int mt = 0; mt < 4; ++mt) {
            const int row = m0 + wr + mt*16 + quad*4;
            const int b = row>>11, i = row & 2047;
            const int tile = (koff + i) >> 6;
            const int slot = 32*(mt>>1) + 4*(mt&1) + 8*quad;
#pragma unroll
            for (int nt = 0; nt < 4; ++nt) {
                uint2 o;
                o.x = pack2bf(acc[mt][nt][0], acc[mt][nt][1]);
                o.y = pack2bf(acc[mt][nt][2], acc[mt][nt][3]);
                *(uint2*)(Vtp + (((size_t)(b*8+hh)*64 + tile)*64 + dp + nt)*64 + slot) = o;
            }
        }
    }
}

// ---------------------------------------------------------------------------
// Output GEMM: out[8192x1024] fp32 = AO[8192x512] bf16 @ Wot[1024x512]^T + bo
// ---------------------------------------------------------------------------
__global__ __launch_bounds__(256) void out_gemm(
    const ushort_t* __restrict__ A, const ushort_t* __restrict__ Bt,
    float* __restrict__ outF, const float* __restrict__ bias)
{
    __shared__ ushort_t As[2][128][32];
    __shared__ ushort_t Bs[2][128][32];
    const int t = threadIdx.x;
    const int m0 = blockIdx.x*128, n0 = blockIdx.y*128;
    const int w = t>>6, l = t&63;
    const int quad = l>>4, lc = l&15;
    const int wr = (w>>1)*64, wc = (w&1)*64;
    const int KD = 512;

    f32x4 acc[4][4] = {};

    const int crow = l>>2;
    const int kseg = (l&3)*8;
    const ushort_t* gA0 = A  + (size_t)(m0 + w*32      + crow)*KD + kseg;
    const ushort_t* gA1 = A  + (size_t)(m0 + w*32 + 16 + crow)*KD + kseg;
    const ushort_t* gB0 = Bt + (size_t)(n0 + w*32      + crow)*KD + kseg;
    const ushort_t* gB1 = Bt + (size_t)(n0 + w*32 + 16 + crow)*KD + kseg;

    async16(&As[0][w*32][0],    gA0);
    async16(&As[0][w*32+16][0], gA1);
    async16(&Bs[0][w*32][0],    gB0);
    async16(&Bs[0][w*32+16][0], gB1);
    __syncthreads();

    for (int kk = 0; kk < 16; ++kk) {
        const int cur = kk & 1;
        if (kk + 1 < 16) {
            const int k0 = (kk+1)*32;
            const int nx = cur ^ 1;
            async16(&As[nx][w*32][0],    gA0 + k0);
            async16(&As[nx][w*32+16][0], gA1 + k0);
            async16(&Bs[nx][w*32][0],    gB0 + k0);
            async16(&Bs[nx][w*32+16][0], gB1 + k0);
        }
        bf16x8 af[4], bfv[4];
#pragma unroll
        for (int i = 0; i < 4; ++i) {
            af[i]  = *(const bf16x8*)&As[cur][wr + i*16 + lc][quad*8];
            bfv[i] = *(const bf16x8*)&Bs[cur][wc + i*16 + lc][quad*8];
        }
#pragma unroll
        for (int mt = 0; mt < 4; ++mt)
#pragma unroll
            for (int nt = 0; nt < 4; ++nt)
                acc[mt][nt] = MFMA16(af[mt], bfv[nt], acc[mt][nt]);
        __syncthreads();
    }

    float bv[4];
#pragma unroll
    for (int nt = 0; nt < 4; ++nt) bv[nt] = bias[n0 + wc + nt*16 + lc];
#pragma unroll
    for (int mt = 0; mt < 4; ++mt) {
        const int row = m0 + wr + mt*16 + quad*4;
#pragma unroll
        for (int nt = 0; nt < 4; ++nt) {
            const int col = n0 + wc + nt*16 + lc;
#pragma unroll
            for (int r = 0; r < 4; ++r)
                outF[(size_t)(row+r)*1024 + col] = acc[mt][nt][r] + bv[nt];
        }
    }
}

// ---------------------------------------------------------------------------
// Flash attention: 128 q/block (2 strips/wave), key-split z=2 (additive
// combine - no-max softmax), dbuf + register prefetch, contiguous K/V tiles.
// Writes fp32 partial O^T and l; reduce_o combines.
// ---------------------------------------------------------------------------
__global__ __launch_bounds__(256) void flash_attn(
    const ushort_t* __restrict__ Q, const ushort_t* __restrict__ Kg,
    const ushort_t* __restrict__ Vt,
    float* __restrict__ O0, float* __restrict__ O1, float* __restrict__ Lp)
{
    __shared__ ushort_t Ks[2][64][72];
    __shared__ ushort_t Vs[2][64][72];
    const int bh = blockIdx.x, qt = blockIdx.y, z = blockIdx.z;
    const int b = bh>>3, h = bh&7;
    const int t = threadIdx.x, wv = t>>6, l = t&63;
    const int quad = l>>4, lc = l&15;

    const ushort_t* qbase = Q + ((size_t)bh*2048 + qt*128 + wv*16 + lc)*64;
    bf16x8 qA0 = *(const bf16x8*)(qbase + quad*8);
    bf16x8 qA1 = *(const bf16x8*)(qbase + 32 + quad*8);
    bf16x8 qB0 = *(const bf16x8*)(qbase + 64*64 + quad*8);
    bf16x8 qB1 = *(const bf16x8*)(qbase + 64*64 + 32 + quad*8);

    const ushort_t* Kb = Kg + ((size_t)bh*4096 + (size_t)z*2048)*64;
    const ushort_t* Vb = Vt + ((size_t)bh*4096 + (size_t)z*2048)*64;

    const int srow = t>>2, sseg = (t&3)*16;
    const ushort_t* kst = Kb + (size_t)t*16;
    const ushort_t* vst = Vb + (size_t)t*16;

    float l0 = 0.0f, l1 = 0.0f;
    f32x4 o0[4] = {}, o1[4] = {};

    uint4 ka  = *(const uint4*)(kst);
    uint4 kb2 = *(const uint4*)(kst + 8);
    uint4 va  = *(const uint4*)(vst);
    uint4 vb2 = *(const uint4*)(vst + 8);

    for (int jt = 0; jt < 32; ++jt) {
        const int cur = jt & 1;
        ushort_t* ksd = &Ks[cur][srow][sseg];
        ushort_t* vsd = &Vs[cur][srow][sseg];
        *(uint4*)ksd     = ka;
        *(uint4*)(ksd+8) = kb2;
        *(uint4*)vsd     = va;
        *(uint4*)(vsd+8) = vb2;
        __syncthreads();
        if (jt < 31) {
            const size_t j0 = (size_t)(jt+1)*4096;
            ka  = *(const uint4*)(kst + j0);
            kb2 = *(const uint4*)(kst + j0 + 8);
            va  = *(const uint4*)(vst + j0);
            vb2 = *(const uint4*)(vst + j0 + 8);
        }

        // S^T for both strips
        f32x4 s0[4], s1[4];
#pragma unroll
        for (int kt = 0; kt < 4; ++kt) {
            bf16x8 kf0 = *(const bf16x8*)&Ks[cur][kt*16 + lc][quad*8];
            bf16x8 kf1 = *(const bf16x8*)&Ks[cur][kt*16 + lc][32 + quad*8];
            f32x4 z0 = {}, z1 = {};
            z0 = MFMA16(kf0, qA0, z0); z0 = MFMA16(kf1, qA1, z0);
            z1 = MFMA16(kf0, qB0, z1); z1 = MFMA16(kf1, qB1, z1);
            s0[kt] = z0; s1[kt] = z1;
        }

        union { unsigned u[8]; bf16x8 v[2]; } p0, p1;
        float rs0 = 0.0f, rs1 = 0.0f;
#pragma unroll
        for (int kt = 0; kt < 4; ++kt) {
            float a0 = fexp2(s0[kt][0]), a1v = fexp2(s0[kt][1]);
            float a2 = fexp2(s0[kt][2]), a3 = fexp2(s0[kt][3]);
            rs0 += (a0 + a1v) + (a2 + a3);
            p0.u[kt*2]   = pack2bf(a0, a1v);
            p0.u[kt*2+1] = pack2bf(a2, a3);
            float c0 = fexp2(s1[kt][0]), c1 = fexp2(s1[kt][1]);
            float c2 = fexp2(s1[kt][2]), c3 = fexp2(s1[kt][3]);
            rs1 += (c0 + c1) + (c2 + c3);
            p1.u[kt*2]   = pack2bf(c0, c1);
            p1.u[kt*2+1] = pack2bf(c2, c3);
        }
        l0 += rs0; l1 += rs1;

#pragma unroll
        for (int dt = 0; dt < 4; ++dt) {
            bf16x8 vf0 = *(const bf16x8*)&Vs[cur][dt*16 + lc][quad*8];
            bf16x8 vf1 = *(const bf16x8*)&Vs[cur][dt*16 + lc][32 + quad*8];
            o0[dt] = MFMA16(vf0, p0.v[0], o0[dt]);
            o0[dt] = MFMA16(vf1, p0.v[1], o0[dt]);
            o1[dt] = MFMA16(vf0, p1.v[0], o1[dt]);
            o1[dt] = MFMA16(vf1, p1.v[1], o1[dt]);
        }
    }

    l0 += __shfl_xor(l0, 16); l0 += __shfl_xor(l0, 32);
    l1 += __shfl_xor(l1, 16); l1 += __shfl_xor(l1, 32);

    float* OP = z ? O1 : O0;
    const int qgA = qt*128 + wv*16 + lc;
    size_t baseA = ((size_t)b*2048 + qgA)*512 + h*64 + quad*4;
    size_t baseB = baseA + (size_t)64*512;
#pragma unroll
    for (int dt = 0; dt < 4; ++dt) {
        *(f32x4*)(OP + baseA + dt*16) = o0[dt];
        *(f32x4*)(OP + baseB + dt*16) = o1[dt];
    }
    if (quad == 0) {
        Lp[(size_t)z*65536 + bh*2048 + qgA]      = l0;
        Lp[(size_t)z*65536 + bh*2048 + qgA + 64] = l1;
    }
}

// ---------------------------------------------------------------------------
// Combine key-split partials: AO = (O0+O1) / (l0+l1), bf16.
// ---------------------------------------------------------------------------
__global__ __launch_bounds__(256) void reduce_o(
    const float* __restrict__ O0, const float* __restrict__ O1,
    const float* __restrict__ Lp, ushort_t* __restrict__ AO)
{
    size_t i = ((size_t)blockIdx.x*256 + threadIdx.x)*4;
    int row = (int)(i >> 9);
    int col = (int)(i & 511);
    int b = row >> 11, q = row & 2047, h = col >> 6;
    size_t li = (size_t)(b*8 + h)*2048 + q;
    float lsum = Lp[li] + Lp[65536 + li];
    float linv = 1.0f / lsum;
    float4 a = *(const float4*)(O0 + i);
    float4 c = *(const float4*)(O1 + i);
    uint2 o;
    o.x = pack2bf((a.x + c.x)*linv, (a.y + c.y)*linv);
    o.y = pack2bf((a.z + c.z)*linv, (a.w + c.w)*linv);
    *(uint2*)(AO + i) = o;
}

// ---------------------------------------------------------------------------
extern "C" void kernel_launch(void* const* d_in, const int* in_sizes, int n_in,
                              void* d_out, int out_size, void* d_ws, size_t ws_size,
                              hipStream_t stream)
{
    const float* x1  = (const float*)d_in[0];
    const float* x2  = (const float*)d_in[1];
    const float* Wq1 = (const float*)d_in[2];
    const float* Wk1 = (const float*)d_in[3];
    const float* Wv1 = (const float*)d_in[4];
    const float* Wk2 = (const float*)d_in[5];
    const float* Wv2 = (const float*)d_in[6];
    const float* Wo  = (const float*)d_in[7];
    const float* bo  = (const float*)d_in[8];
    float* out = (float*)d_out;

    ushort_t* ws  = (ushort_t*)d_ws;
    ushort_t* Xc1 = ws;                 // 8,388,608 ushort; after proj: Opart0 (fp32, same bytes)
    ushort_t* Xc2 = Xc1 + 8388608;      // 8,388,608 ushort; after proj: Opart1
    ushort_t* Wt1 = Xc2 + 8388608;      // 1,572,864; after proj: Lp (fp32, 131072 floats)
    ushort_t* Wt2 = Wt1 + 1572864;      // 1,048,576
    ushort_t* Wot = Wt2 + 1048576;      //   524,288
    ushort_t* Qp  = Wot + 524288;       // 4,194,304; after flash: AO (bf16)
    ushort_t* Kp  = Qp  + 4194304;      // 8,388,608
    ushort_t* Vtp = Kp  + 8388608;      // 8,388,608   total 81.8 MB

    float* Opart0 = (float*)Xc1;
    float* Opart1 = (float*)Xc2;
    float* Lp     = (float*)Wt1;
    ushort_t* AOp = Qp;

    convert_x<<<4096, 256, 0, stream>>>(x1, Xc1);
    convert_x<<<4096, 256, 0, stream>>>(x2, Xc2);
    transpose_w<<<dim3(32,16,5), 256, 0, stream>>>(Wq1,Wk1,Wv1,Wk2,Wv2, Wt1,Wt2);
    transpose_wo<<<dim3(8,32), 256, 0, stream>>>(Wo, Wot);

    proj_fused<<<dim3(64,20), 256, 0, stream>>>(Xc1, Xc2, Wt1, Wt2, Qp, Kp, Vtp);

    flash_attn<<<dim3(32,16,2), 256, 0, stream>>>(Qp, Kp, Vtp, Opart0, Opart1, Lp);

    reduce_o<<<4096, 256, 0, stream>>>(Opart0, Opart1, Lp, AOp);

    out_gemm<<<dim3(64,8), 256, 0, stream>>>(AOp, Wot, out, bo);
}